// Round 4
// baseline (144.099 us; speedup 1.0000x reference)
//
#include <hip/hip_runtime.h>
#include <hip/hip_bf16.h>

// ---------------------------------------------------------------------------
// Triplet loss, 8-phase 256^2 MFMA GEMM (R2 schedule + 32x32x16 MFMA):
//   D1[i,j] = || (v_f[j]+eps) - i_f[i] ||,  D2[i,j] = || (i_f[j]+eps) - v_f[i] ||
//   per row: same_max = max over same-label D, diff_min = min over diff-label D
//   loss = sum relu(same_max - diff_min + 1.2) over both matrices.
// sq-domain trick: reduce on squared distances, sqrt once per row.
// Stage ledger (R2, known-good 86us): per iteration over tile t (buffer c):
//   ph0: stage A-h1(t+1)->c^1   ph1: stage B-h0(t+1)->c^1
//   ph2: stage B-h1(t+1)->c^1   ph3: stage A-h0(t+2)->c, vmcnt(2)
// ---------------------------------------------------------------------------

#define MDIM 4096
#define KDIM 1024
#define NT   16      // K-tiles of 64

typedef __attribute__((ext_vector_type(16))) float f32x16;
typedef __attribute__((ext_vector_type(8)))  short bf16x8;

__device__ __forceinline__ void gload16(const void* g, void* l) {
  __builtin_amdgcn_global_load_lds(
      (const __attribute__((address_space(1))) void*)g,
      (__attribute__((address_space(3))) void*)l,
      16, 0, 0);
}

__device__ __forceinline__ unsigned short f2bf(float x) {
  unsigned int u = __float_as_uint(x);
  unsigned int r = (u + 0x7FFFu + ((u >> 16) & 1u)) >> 16;  // RNE
  return (unsigned short)r;
}

#define BAR() do { asm volatile("" ::: "memory"); \
                   __builtin_amdgcn_s_barrier();  \
                   asm volatile("" ::: "memory"); } while (0)

// --- prep: f32 -> bf16 copies, row norms of x and x+eps (exact f32) --------
__global__ __launch_bounds__(256) void prep_kernel(
    const float* __restrict__ vf, const float* __restrict__ iff,
    unsigned short* __restrict__ vb, unsigned short* __restrict__ ib,
    float* __restrict__ nv, float* __restrict__ ni,
    float* __restrict__ nvp, float* __restrict__ nip) {
  const int b = blockIdx.x;             // 0..8191
  const int mat = b >> 12;              // 0 = v_f, 1 = i_f
  const int row = b & 4095;
  const float* X = mat ? iff : vf;
  unsigned short* Xb = mat ? ib : vb;
  float* n0 = mat ? ni : nv;
  float* n1 = mat ? nip : nvp;

  const int t = threadIdx.x;
  const float4* xr4 = (const float4*)(X + (size_t)row * KDIM);
  ushort4* xb4 = (ushort4*)(Xb + (size_t)row * KDIM);

  float4 v = xr4[t];
  float s0 = v.x * v.x + v.y * v.y + v.z * v.z + v.w * v.w;
  float ex = v.x + 1e-6f, ey = v.y + 1e-6f, ez = v.z + 1e-6f, ew = v.w + 1e-6f;
  float s1 = ex * ex + ey * ey + ez * ez + ew * ew;
  ushort4 o;
  o.x = f2bf(v.x); o.y = f2bf(v.y); o.z = f2bf(v.z); o.w = f2bf(v.w);
  xb4[t] = o;

  for (int off = 32; off; off >>= 1) {
    s0 += __shfl_down(s0, off);
    s1 += __shfl_down(s1, off);
  }
  __shared__ float r0[4], r1[4];
  const int w = t >> 6, lane = t & 63;
  if (lane == 0) { r0[w] = s0; r1[w] = s1; }
  __syncthreads();
  if (t == 0) {
    n0[row] = r0[0] + r0[1] + r0[2] + r0[3];
    n1[row] = r1[0] + r1[1] + r1[2] + r1[3];
  }
}

// --- init the atomic max/min buffers ---------------------------------------
__global__ __launch_bounds__(256) void init_kernel(int* __restrict__ same_sq,
                                                   int* __restrict__ diff_sq) {
  const int i = blockIdx.x * 256 + threadIdx.x;  // 8192 total
  same_sq[i] = 0;                                // sq >= 0, so 0 is max-identity
  diff_sq[i] = 0x7F800000;                       // +inf
}

// --- fused 256x256 8-phase GEMM + distance + masked row max/min ------------
// dir 0: A = i_f (anchor), B = v_f (+eps norms).  dir 1: A = v_f, B = i_f.
__global__ __launch_bounds__(512, 2) void tri_gemm(
    const unsigned short* __restrict__ vb, const unsigned short* __restrict__ ib,
    const float* __restrict__ nv, const float* __restrict__ ni,
    const float* __restrict__ nvp, const float* __restrict__ nip,
    const int* __restrict__ y,
    int* __restrict__ same_sq, int* __restrict__ diff_sq) {
  // K-tile buffer: [256 rows][64 k] bf16, row = 128 B, 8 chunks of 16 B.
  // XOR swizzle: data for (row, chunk) lives at (row, chunk ^ (row&7)).
  // global_load_lds dest stays linear; source address is pre-swizzled.
  __shared__ unsigned short Abuf[2][256][64];   // 64 KiB
  __shared__ unsigned short Bbuf[2][256][64];   // 64 KiB
  __shared__ int   yrow[256], ycol[256];
  __shared__ float nAr[256], nBc[256];

  const int dir = blockIdx.z;
  const unsigned short* Amat = dir ? vb : ib;
  const unsigned short* Bmat = dir ? ib : vb;
  const float* nA = dir ? nv : ni;
  const float* nB = dir ? nip : nvp;

  const int row0 = blockIdx.y * 256;
  const int col0 = blockIdx.x * 256;

  const int t = threadIdx.x;
  const int w = t >> 6, lane = t & 63;
  const int l32 = lane & 31, hi = lane >> 5;
  const int wr = w >> 2, wc = w & 3;            // 2 x 4 waves -> 128 x 64 tile

  // stage one half-tile (128 rows x 64 k = 16 KB) = 2 gload16 per thread
  auto stage = [&](const unsigned short* __restrict__ X, int tile0,
                   unsigned short (&buf)[256][64], int h, int k0s) {
#pragma unroll
    for (int r = 0; r < 2; ++r) {
      const int row = h * 128 + r * 64 + (t >> 3);
      const int chunk = t & 7;
      const unsigned short* src =
          X + (size_t)(tile0 + row) * KDIM + k0s + ((chunk ^ (row & 7)) << 3);
      gload16(src, &buf[h * 128 + r * 64 + (w << 3)][0]);
    }
  };
  // 32x32x16 fragments: A row=lane&31, k=(lane>>5)*8+e; B col=lane&31 same.
  auto ldA = [&](int c, int rb, int ks) -> bf16x8 {
    const int row = wr * 128 + rb * 32 + l32;
    const int chunk = ((ks << 1) | hi) ^ (row & 7);
    return *(const bf16x8*)&Abuf[c][row][chunk << 3];
  };
  auto ldB = [&](int c, int nb, int ks) -> bf16x8 {
    const int col = wc * 64 + nb * 32 + l32;
    const int chunk = ((ks << 1) | hi) ^ (col & 7);
    return *(const bf16x8*)&Bbuf[c][col][chunk << 3];
  };

  // ---- prologue: tile 0 fully + tile 1 A-h0; labels/norms ----
  stage(Amat, row0, Abuf[0], 0, 0);
  stage(Amat, row0, Abuf[0], 1, 0);
  stage(Bmat, col0, Bbuf[0], 0, 0);
  stage(Bmat, col0, Bbuf[0], 1, 0);
  stage(Amat, row0, Abuf[1], 0, 64);
  if (t < 256) {
    yrow[t] = y[row0 + t];
    nAr[t] = nA[row0 + t];
  } else {
    const int c = t - 256;
    ycol[c] = y[col0 + c];
    nBc[c] = nB[col0 + c];
  }
  __syncthreads();   // full drain once; counted vmcnt from here on

  f32x16 acc[4][2] = {};
  bf16x8 aF[2][4], bF0[4], bF1[4];

  int cur = 0;
  for (int kt = 0; kt < NT; ++kt) {
    const int nxt = cur ^ 1;
    const int k1 = ((kt + 1) & (NT - 1)) * 64;
    const int k2 = ((kt + 2) & (NT - 1)) * 64;

    // ---- phase 0: row-blocks {0,1} x col-block 0; stage A-h1(t+1) ----
#pragma unroll
    for (int rb = 0; rb < 2; ++rb)
#pragma unroll
      for (int ks = 0; ks < 4; ++ks) aF[rb][ks] = ldA(cur, rb, ks);
#pragma unroll
    for (int ks = 0; ks < 4; ++ks) bF0[ks] = ldB(cur, 0, ks);
    stage(Amat, row0, Abuf[nxt], 1, k1);
    BAR();
    __builtin_amdgcn_s_setprio(1);
#pragma unroll
    for (int rb = 0; rb < 2; ++rb)
#pragma unroll
      for (int ks = 0; ks < 4; ++ks)
        acc[rb][0] = __builtin_amdgcn_mfma_f32_32x32x16_bf16(aF[rb][ks], bF0[ks], acc[rb][0], 0, 0, 0);
    __builtin_amdgcn_s_setprio(0);
    BAR();

    // ---- phase 1: row-blocks {0,1} x col-block 1; stage B-h0(t+1) ----
#pragma unroll
    for (int ks = 0; ks < 4; ++ks) bF1[ks] = ldB(cur, 1, ks);
    stage(Bmat, col0, Bbuf[nxt], 0, k1);
    BAR();
    __builtin_amdgcn_s_setprio(1);
#pragma unroll
    for (int rb = 0; rb < 2; ++rb)
#pragma unroll
      for (int ks = 0; ks < 4; ++ks)
        acc[rb][1] = __builtin_amdgcn_mfma_f32_32x32x16_bf16(aF[rb][ks], bF1[ks], acc[rb][1], 0, 0, 0);
    __builtin_amdgcn_s_setprio(0);
    BAR();

    // ---- phase 2: row-blocks {2,3} x col-block 0; stage B-h1(t+1) ----
#pragma unroll
    for (int rb = 0; rb < 2; ++rb)
#pragma unroll
      for (int ks = 0; ks < 4; ++ks) aF[rb][ks] = ldA(cur, 2 + rb, ks);
    stage(Bmat, col0, Bbuf[nxt], 1, k1);
    BAR();
    __builtin_amdgcn_s_setprio(1);
#pragma unroll
    for (int rb = 0; rb < 2; ++rb)
#pragma unroll
      for (int ks = 0; ks < 4; ++ks)
        acc[2 + rb][0] = __builtin_amdgcn_mfma_f32_32x32x16_bf16(aF[rb][ks], bF0[ks], acc[2 + rb][0], 0, 0, 0);
    __builtin_amdgcn_s_setprio(0);
    BAR();

    // ---- phase 3: row-blocks {2,3} x col-block 1; stage A-h0(t+2) into cur;
    //      counted wait: newest 2 (just-issued) stay in flight ----
    stage(Amat, row0, Abuf[cur], 0, k2);
    asm volatile("s_waitcnt vmcnt(2)" ::: "memory");
    BAR();
    __builtin_amdgcn_s_setprio(1);
#pragma unroll
    for (int rb = 0; rb < 2; ++rb)
#pragma unroll
      for (int ks = 0; ks < 4; ++ks)
        acc[2 + rb][1] = __builtin_amdgcn_mfma_f32_32x32x16_bf16(aF[rb][ks], bF1[ks], acc[2 + rb][1], 0, 0, 0);
    __builtin_amdgcn_s_setprio(0);
    BAR();

    cur = nxt;
  }
  asm volatile("s_waitcnt vmcnt(0)" ::: "memory");

  // ---- epilogue: sq distance + mask + per-row reduce over tile's 256 cols --
  // C/D 32x32: col = lane&31, row = (reg&3) + 8*(reg>>2) + 4*(lane>>5)
  const int rbase = dir * MDIM + row0;
#pragma unroll
  for (int R = 0; R < 4; ++R) {
#pragma unroll
    for (int r16 = 0; r16 < 16; ++r16) {
      const int row_loc = wr * 128 + R * 32 + (r16 & 3) + 8 * (r16 >> 2) + 4 * hi;
      const float na = nAr[row_loc];
      const int yl = yrow[row_loc];
      float smax = 0.0f;
      float dmin = __int_as_float(0x7F800000);
#pragma unroll
      for (int Cb = 0; Cb < 2; ++Cb) {
        const int col_loc = wc * 64 + Cb * 32 + l32;
        const float sq = fmaxf(na + nBc[col_loc] - 2.0f * acc[R][Cb][r16], 0.0f);
        if (ycol[col_loc] == yl) smax = fmaxf(smax, sq);
        else                     dmin = fminf(dmin, sq);
      }
#pragma unroll
      for (int off = 1; off < 32; off <<= 1) {
        smax = fmaxf(smax, __shfl_xor(smax, off));
        dmin = fminf(dmin, __shfl_xor(dmin, off));
      }
      if (l32 == 0) {
        // nonneg floats: int compare == float compare -> order-independent
        atomicMax(&same_sq[rbase + row_loc], __float_as_int(smax));
        atomicMin(&diff_sq[rbase + row_loc], __float_as_int(dmin));
      }
    }
  }
}

// --- finalize: sqrt, relu, sum ---------------------------------------------
__global__ __launch_bounds__(256) void finalize_kernel(
    const int* __restrict__ same_sq, const int* __restrict__ diff_sq,
    float* __restrict__ out) {
  const int i = blockIdx.x * 256 + threadIdx.x;  // 8192 total
  const float sm = sqrtf(__int_as_float(same_sq[i]));
  const float dm = sqrtf(__int_as_float(diff_sq[i]));  // +inf if no diff label
  float l = fmaxf(sm - dm + 1.2f, 0.0f);
  for (int off = 32; off; off >>= 1) l += __shfl_down(l, off);
  __shared__ float part[4];
  const int w = threadIdx.x >> 6, lane = threadIdx.x & 63;
  if (lane == 0) part[w] = l;
  __syncthreads();
  if (threadIdx.x == 0) atomicAdd(out, part[0] + part[1] + part[2] + part[3]);
}

extern "C" void kernel_launch(void* const* d_in, const int* in_sizes, int n_in,
                              void* d_out, int out_size, void* d_ws, size_t ws_size,
                              hipStream_t stream) {
  const float* vf = (const float*)d_in[0];
  const float* iff = (const float*)d_in[1];
  const int* y = (const int*)d_in[2];
  float* out = (float*)d_out;

  char* ws = (char*)d_ws;
  unsigned short* vb = (unsigned short*)ws;                       // 8 MB
  unsigned short* ib = (unsigned short*)(ws + (8u << 20));        // 8 MB
  float* nv  = (float*)(ws + (16u << 20));
  float* ni  = nv + 4096;
  float* nvp = nv + 2 * 4096;
  float* nip = nv + 3 * 4096;
  int* same_sq = (int*)(nv + 4 * 4096);                           // [2][4096]
  int* diff_sq = same_sq + 2 * 4096;                              // [2][4096]

  hipMemsetAsync(d_out, 0, sizeof(float), stream);
  init_kernel<<<32, 256, 0, stream>>>(same_sq, diff_sq);
  prep_kernel<<<8192, 256, 0, stream>>>(vf, iff, vb, ib, nv, ni, nvp, nip);
  tri_gemm<<<dim3(16, 16, 2), 512, 0, stream>>>(vb, ib, nv, ni, nvp, nip, y,
                                                same_sq, diff_sq);
  finalize_kernel<<<32, 256, 0, stream>>>(same_sq, diff_sq, out);
}

// Round 5
// 101.839 us; speedup vs baseline: 1.4150x; 1.4150x over previous
//
#include <hip/hip_runtime.h>
#include <hip/hip_bf16.h>

// ---------------------------------------------------------------------------
// Triplet loss, 8-phase 256^2 MFMA GEMM (R2 structure + redistributed counted
// vmcnt waits, T3/T4 per m218):
//   D1[i,j] = || (v_f[j]+eps) - i_f[i] ||,  D2[i,j] = || (i_f[j]+eps) - v_f[i] ||
//   per row: same_max = max over same-label D, diff_min = min over diff-label D
//   loss = sum relu(same_max - diff_min + 1.2) over both matrices.
// sq-domain trick: reduce on squared distances, sqrt once per row.
// Stage ledger per iteration over tile t (buffer c):
//   ph0: stage A-h1(t+1)->c^1 ; end: vmcnt(4)  (drains B-h1(t), 2-phase slack)
//   ph1: stage B-h0(t+1)->c^1
//   ph2: stage B-h1(t+1)->c^1
//   ph3: stage A-h0(t+2)->c   ; end: vmcnt(4)  (drains B-h0(t+1), 2-phase slack)
// Queue at ph3-end: [Ah0(t+1) Ah1(t+1) Bh0(t+1) | Bh1(t+1) Ah0(t+2)]x2.
// ---------------------------------------------------------------------------

#define MDIM 4096
#define KDIM 1024
#define NT   16      // K-tiles of 64

typedef __attribute__((ext_vector_type(4))) float  f32x4;
typedef __attribute__((ext_vector_type(8))) short  bf16x8;

__device__ __forceinline__ void gload16(const void* g, void* l) {
  __builtin_amdgcn_global_load_lds(
      (const __attribute__((address_space(1))) void*)g,
      (__attribute__((address_space(3))) void*)l,
      16, 0, 0);
}

__device__ __forceinline__ unsigned short f2bf(float x) {
  unsigned int u = __float_as_uint(x);
  unsigned int r = (u + 0x7FFFu + ((u >> 16) & 1u)) >> 16;  // RNE
  return (unsigned short)r;
}

#define BAR() do { asm volatile("" ::: "memory"); \
                   __builtin_amdgcn_s_barrier();  \
                   asm volatile("" ::: "memory"); } while (0)

// --- prep: f32 -> bf16 copies, row norms of x and x+eps (exact f32) --------
__global__ __launch_bounds__(256) void prep_kernel(
    const float* __restrict__ vf, const float* __restrict__ iff,
    unsigned short* __restrict__ vb, unsigned short* __restrict__ ib,
    float* __restrict__ nv, float* __restrict__ ni,
    float* __restrict__ nvp, float* __restrict__ nip) {
  const int b = blockIdx.x;             // 0..8191
  const int mat = b >> 12;              // 0 = v_f, 1 = i_f
  const int row = b & 4095;
  const float* X = mat ? iff : vf;
  unsigned short* Xb = mat ? ib : vb;
  float* n0 = mat ? ni : nv;
  float* n1 = mat ? nip : nvp;

  const int t = threadIdx.x;
  const float4* xr4 = (const float4*)(X + (size_t)row * KDIM);
  ushort4* xb4 = (ushort4*)(Xb + (size_t)row * KDIM);

  float4 v = xr4[t];
  float s0 = v.x * v.x + v.y * v.y + v.z * v.z + v.w * v.w;
  float ex = v.x + 1e-6f, ey = v.y + 1e-6f, ez = v.z + 1e-6f, ew = v.w + 1e-6f;
  float s1 = ex * ex + ey * ey + ez * ez + ew * ew;
  ushort4 o;
  o.x = f2bf(v.x); o.y = f2bf(v.y); o.z = f2bf(v.z); o.w = f2bf(v.w);
  xb4[t] = o;

  for (int off = 32; off; off >>= 1) {
    s0 += __shfl_down(s0, off);
    s1 += __shfl_down(s1, off);
  }
  __shared__ float r0[4], r1[4];
  const int w = t >> 6, lane = t & 63;
  if (lane == 0) { r0[w] = s0; r1[w] = s1; }
  __syncthreads();
  if (t == 0) {
    n0[row] = r0[0] + r0[1] + r0[2] + r0[3];
    n1[row] = r1[0] + r1[1] + r1[2] + r1[3];
  }
}

// --- init the atomic max/min buffers ---------------------------------------
__global__ __launch_bounds__(256) void init_kernel(int* __restrict__ same_sq,
                                                   int* __restrict__ diff_sq) {
  const int i = blockIdx.x * 256 + threadIdx.x;  // 8192 total
  same_sq[i] = 0;                                // sq >= 0, so 0 is max-identity
  diff_sq[i] = 0x7F800000;                       // +inf
}

// --- fused 256x256 8-phase GEMM + distance + masked row max/min ------------
// dir 0: A = i_f (anchor), B = v_f (+eps norms).  dir 1: A = v_f, B = i_f.
__global__ __launch_bounds__(512, 2) void tri_gemm(
    const unsigned short* __restrict__ vb, const unsigned short* __restrict__ ib,
    const float* __restrict__ nv, const float* __restrict__ ni,
    const float* __restrict__ nvp, const float* __restrict__ nip,
    const int* __restrict__ y,
    int* __restrict__ same_sq, int* __restrict__ diff_sq) {
  // K-tile buffer: [256 rows][64 k] bf16, row = 128 B, 8 chunks of 16 B.
  // XOR swizzle: data for (row, chunk) lives at (row, chunk ^ (row&7)).
  // global_load_lds dest stays linear; source address is pre-swizzled.
  __shared__ unsigned short Abuf[2][256][64];   // 64 KiB
  __shared__ unsigned short Bbuf[2][256][64];   // 64 KiB
  __shared__ int   yrow[256], ycol[256];
  __shared__ float nAr[256], nBc[256];

  const int dir = blockIdx.z;
  const unsigned short* Amat = dir ? vb : ib;
  const unsigned short* Bmat = dir ? ib : vb;
  const float* nA = dir ? nv : ni;
  const float* nB = dir ? nip : nvp;

  const int row0 = blockIdx.y * 256;
  const int col0 = blockIdx.x * 256;

  const int t = threadIdx.x;
  const int w = t >> 6, lane = t & 63;
  const int lr = lane & 15, lg = lane >> 4;
  const int wr = w >> 2, wc = w & 3;            // 2 x 4 waves -> 128 x 64 tile

  // stage one half-tile (128 rows x 64 k = 16 KB) = 2 gload16 per thread
  auto stage = [&](const unsigned short* __restrict__ X, int tile0,
                   unsigned short (&buf)[256][64], int h, int k0s) {
#pragma unroll
    for (int r = 0; r < 2; ++r) {
      const int row = h * 128 + r * 64 + (t >> 3);
      const int chunk = t & 7;
      const unsigned short* src =
          X + (size_t)(tile0 + row) * KDIM + k0s + ((chunk ^ (row & 7)) << 3);
      gload16(src, &buf[h * 128 + r * 64 + (w << 3)][0]);
    }
  };
  auto ldA = [&](int c, int mh, int m, int ks) -> bf16x8 {
    const int row = wr * 128 + mh * 64 + m * 16 + lr;
    const int chunk = ((ks << 2) | lg) ^ (row & 7);
    return *(const bf16x8*)&Abuf[c][row][chunk << 3];
  };
  auto ldB = [&](int c, int nh, int n, int ks) -> bf16x8 {
    const int col = wc * 64 + nh * 32 + n * 16 + lr;
    const int chunk = ((ks << 2) | lg) ^ (col & 7);
    return *(const bf16x8*)&Bbuf[c][col][chunk << 3];
  };

  // ---- prologue: tile 0 fully + tile 1 A-h0; labels/norms ----
  // Queue: [Ah0(0) Ah1(0) Bh0(0) | Bh1(0) Ah0(1)] x2 loads each.
  stage(Amat, row0, Abuf[0], 0, 0);
  stage(Amat, row0, Abuf[0], 1, 0);
  stage(Bmat, col0, Bbuf[0], 0, 0);
  stage(Bmat, col0, Bbuf[0], 1, 0);
  stage(Amat, row0, Abuf[1], 0, 64);
  if (t < 256) {
    yrow[t] = y[row0 + t];
    nAr[t] = nA[row0 + t];
  } else {
    const int c = t - 256;
    ycol[c] = y[col0 + c];
    nBc[c] = nB[col0 + c];
  }
  // counted entry: keep Bh1(0)+Ah0(1) in flight; drain LDS writes of y/n.
  asm volatile("s_waitcnt vmcnt(4) lgkmcnt(0)" ::: "memory");
  BAR();

  f32x4 acc[8][4] = {};
  bf16x8 aF[4][2], bF0[2][2], bF1[2][2];

  int cur = 0;
  for (int kt = 0; kt < NT; ++kt) {
    const int nxt = cur ^ 1;
    const int k1 = ((kt + 1) & (NT - 1)) * 64;
    const int k2 = ((kt + 2) & (NT - 1)) * 64;

    // ---- phase 0: quadrant (mh=0) x bF0; stage A-h1(t+1) ----
#pragma unroll
    for (int m = 0; m < 4; ++m) {
      aF[m][0] = ldA(cur, 0, m, 0);
      aF[m][1] = ldA(cur, 0, m, 1);
    }
#pragma unroll
    for (int n = 0; n < 2; ++n) {
      bF0[n][0] = ldB(cur, 0, n, 0);
      bF0[n][1] = ldB(cur, 0, n, 1);
    }
    stage(Amat, row0, Abuf[nxt], 1, k1);
    BAR();
    __builtin_amdgcn_s_setprio(1);
#pragma unroll
    for (int m = 0; m < 4; ++m)
#pragma unroll
      for (int n = 0; n < 2; ++n) {
        acc[m][n] = __builtin_amdgcn_mfma_f32_16x16x32_bf16(aF[m][0], bF0[n][0], acc[m][n], 0, 0, 0);
        acc[m][n] = __builtin_amdgcn_mfma_f32_16x16x32_bf16(aF[m][1], bF0[n][1], acc[m][n], 0, 0, 0);
      }
    __builtin_amdgcn_s_setprio(0);
    // drain B-h1(t) (issued 2 phases ago) for ph1's reads; keep 4 in flight
    asm volatile("s_waitcnt vmcnt(4)" ::: "memory");
    BAR();

    // ---- phase 1: quadrant (mh=0) x bF1; stage B-h0(t+1) ----
#pragma unroll
    for (int n = 0; n < 2; ++n) {
      bF1[n][0] = ldB(cur, 1, n, 0);
      bF1[n][1] = ldB(cur, 1, n, 1);
    }
    stage(Bmat, col0, Bbuf[nxt], 0, k1);
    BAR();
    __builtin_amdgcn_s_setprio(1);
#pragma unroll
    for (int m = 0; m < 4; ++m)
#pragma unroll
      for (int n = 0; n < 2; ++n) {
        acc[m][2 + n] = __builtin_amdgcn_mfma_f32_16x16x32_bf16(aF[m][0], bF1[n][0], acc[m][2 + n], 0, 0, 0);
        acc[m][2 + n] = __builtin_amdgcn_mfma_f32_16x16x32_bf16(aF[m][1], bF1[n][1], acc[m][2 + n], 0, 0, 0);
      }
    __builtin_amdgcn_s_setprio(0);
    BAR();

    // ---- phase 2: quadrant (mh=1) x bF0; stage B-h1(t+1) ----
    // (A-h1(t) was drained by the previous iteration's ph3 wait)
#pragma unroll
    for (int m = 0; m < 4; ++m) {
      aF[m][0] = ldA(cur, 1, m, 0);
      aF[m][1] = ldA(cur, 1, m, 1);
    }
    stage(Bmat, col0, Bbuf[nxt], 1, k1);
    BAR();
    __builtin_amdgcn_s_setprio(1);
#pragma unroll
    for (int m = 0; m < 4; ++m)
#pragma unroll
      for (int n = 0; n < 2; ++n) {
        acc[4 + m][n] = __builtin_amdgcn_mfma_f32_16x16x32_bf16(aF[m][0], bF0[n][0], acc[4 + m][n], 0, 0, 0);
        acc[4 + m][n] = __builtin_amdgcn_mfma_f32_16x16x32_bf16(aF[m][1], bF0[n][1], acc[4 + m][n], 0, 0, 0);
      }
    __builtin_amdgcn_s_setprio(0);
    BAR();

    // ---- phase 3: quadrant (mh=1) x bF1 (no new ds_reads); stage A-h0(t+2)
    //      into buf[cur] (A region read-complete at ph2) ----
    stage(Amat, row0, Abuf[cur], 0, k2);
    BAR();
    __builtin_amdgcn_s_setprio(1);
#pragma unroll
    for (int m = 0; m < 4; ++m)
#pragma unroll
      for (int n = 0; n < 2; ++n) {
        acc[4 + m][2 + n] = __builtin_amdgcn_mfma_f32_16x16x32_bf16(aF[m][0], bF1[n][0], acc[4 + m][2 + n], 0, 0, 0);
        acc[4 + m][2 + n] = __builtin_amdgcn_mfma_f32_16x16x32_bf16(aF[m][1], bF1[n][1], acc[4 + m][2 + n], 0, 0, 0);
      }
    __builtin_amdgcn_s_setprio(0);
    // drain B-h0(t+1) (issued 2 phases ago) for next ph0; keep 4 in flight
    asm volatile("s_waitcnt vmcnt(4)" ::: "memory");
    BAR();

    cur = nxt;
  }
  asm volatile("s_waitcnt vmcnt(0)" ::: "memory");

  // ---- epilogue: sq distance + mask + per-row reduce over tile's 256 cols --
  // (stray tail stages write only Abuf/Bbuf, never yrow/ycol/nAr/nBc)
  const int rbase = dir * MDIM + row0;
#pragma unroll
  for (int M = 0; M < 8; ++M) {
#pragma unroll
    for (int r = 0; r < 4; ++r) {
      const int row_loc = wr * 128 + M * 16 + lg * 4 + r;
      const float na = nAr[row_loc];
      const int yl = yrow[row_loc];
      float smax = 0.0f;
      float dmin = __int_as_float(0x7F800000);
#pragma unroll
      for (int N = 0; N < 4; ++N) {
        const int col_loc = wc * 64 + N * 16 + lr;
        const float sq = fmaxf(na + nBc[col_loc] - 2.0f * acc[M][N][r], 0.0f);
        if (ycol[col_loc] == yl) smax = fmaxf(smax, sq);
        else                     dmin = fminf(dmin, sq);
      }
#pragma unroll
      for (int off = 1; off < 16; off <<= 1) {
        smax = fmaxf(smax, __shfl_xor(smax, off));
        dmin = fminf(dmin, __shfl_xor(dmin, off));
      }
      if (lr == 0) {
        // nonneg floats: int compare == float compare -> order-independent
        atomicMax(&same_sq[rbase + row_loc], __float_as_int(smax));
        atomicMin(&diff_sq[rbase + row_loc], __float_as_int(dmin));
      }
    }
  }
}

// --- finalize: sqrt, relu, sum ---------------------------------------------
__global__ __launch_bounds__(256) void finalize_kernel(
    const int* __restrict__ same_sq, const int* __restrict__ diff_sq,
    float* __restrict__ out) {
  const int i = blockIdx.x * 256 + threadIdx.x;  // 8192 total
  const float sm = sqrtf(__int_as_float(same_sq[i]));
  const float dm = sqrtf(__int_as_float(diff_sq[i]));  // +inf if no diff label
  float l = fmaxf(sm - dm + 1.2f, 0.0f);
  for (int off = 32; off; off >>= 1) l += __shfl_down(l, off);
  __shared__ float part[4];
  const int w = threadIdx.x >> 6, lane = threadIdx.x & 63;
  if (lane == 0) part[w] = l;
  __syncthreads();
  if (threadIdx.x == 0) atomicAdd(out, part[0] + part[1] + part[2] + part[3]);
}

extern "C" void kernel_launch(void* const* d_in, const int* in_sizes, int n_in,
                              void* d_out, int out_size, void* d_ws, size_t ws_size,
                              hipStream_t stream) {
  const float* vf = (const float*)d_in[0];
  const float* iff = (const float*)d_in[1];
  const int* y = (const int*)d_in[2];
  float* out = (float*)d_out;

  char* ws = (char*)d_ws;
  unsigned short* vb = (unsigned short*)ws;                       // 8 MB
  unsigned short* ib = (unsigned short*)(ws + (8u << 20));        // 8 MB
  float* nv  = (float*)(ws + (16u << 20));
  float* ni  = nv + 4096;
  float* nvp = nv + 2 * 4096;
  float* nip = nv + 3 * 4096;
  int* same_sq = (int*)(nv + 4 * 4096);                           // [2][4096]
  int* diff_sq = same_sq + 2 * 4096;                              // [2][4096]

  hipMemsetAsync(d_out, 0, sizeof(float), stream);
  init_kernel<<<32, 256, 0, stream>>>(same_sq, diff_sq);
  prep_kernel<<<8192, 256, 0, stream>>>(vf, iff, vb, ib, nv, ni, nvp, nip);
  tri_gemm<<<dim3(16, 16, 2), 512, 0, stream>>>(vb, ib, nv, ni, nvp, nip, y,
                                                same_sq, diff_sq);
  finalize_kernel<<<32, 256, 0, stream>>>(same_sq, diff_sq, out);
}

// Round 6
// 65.717 us; speedup vs baseline: 2.1927x; 1.5497x over previous
//
#include <hip/hip_runtime.h>
#include <hip/hip_bf16.h>

// ---------------------------------------------------------------------------
// Triplet loss via ONE 4096^2 sq-distance GEMM (transpose symmetry):
//   G[i,j] = ||i_f[i]||^2 + ||v_f[j]+eps||^2 - 2 i_f[i].(v_f[j]+eps)
//   loss_i: per row i  (anchor i_f[i]): max same-label G, min diff-label G
//   loss_v: per col j  (anchor v_f[j]): max same-label G, min diff-label G
//   (exact dir-2 sq differs by 4*eps*(S_i - S_v) ~ 2.6e-4 on sq ~ 2048 -> noise)
// sq-domain trick: reduce on squared distances, sqrt once per anchor.
// Stage ledger (R2/R5 schedule, known-good): per iteration over tile t (buf c):
//   ph0: stage A-h1(t+1)->c^1 ; end vmcnt(4)   ph1: stage B-h0(t+1)->c^1
//   ph2: stage B-h1(t+1)->c^1                  ph3: stage A-h0(t+2)->c ; vmcnt(4)
// ---------------------------------------------------------------------------

#define MDIM 4096
#define KDIM 1024
#define NT   16      // K-tiles of 64

typedef __attribute__((ext_vector_type(4))) float  f32x4;
typedef __attribute__((ext_vector_type(8))) short  bf16x8;

__device__ __forceinline__ void gload16(const void* g, void* l) {
  __builtin_amdgcn_global_load_lds(
      (const __attribute__((address_space(1))) void*)g,
      (__attribute__((address_space(3))) void*)l,
      16, 0, 0);
}

__device__ __forceinline__ unsigned short f2bf(float x) {
  unsigned int u = __float_as_uint(x);
  unsigned int r = (u + 0x7FFFu + ((u >> 16) & 1u)) >> 16;  // RNE
  return (unsigned short)r;
}

#define BAR() do { asm volatile("" ::: "memory"); \
                   __builtin_amdgcn_s_barrier();  \
                   asm volatile("" ::: "memory"); } while (0)

// --- prep: f32 -> bf16 copies, row norms of x and x+eps (exact f32) --------
__global__ __launch_bounds__(256) void prep_kernel(
    const float* __restrict__ vf, const float* __restrict__ iff,
    unsigned short* __restrict__ vb, unsigned short* __restrict__ ib,
    float* __restrict__ nv, float* __restrict__ ni,
    float* __restrict__ nvp, float* __restrict__ nip) {
  const int b = blockIdx.x;             // 0..8191
  const int mat = b >> 12;              // 0 = v_f, 1 = i_f
  const int row = b & 4095;
  const float* X = mat ? iff : vf;
  unsigned short* Xb = mat ? ib : vb;
  float* n0 = mat ? ni : nv;
  float* n1 = mat ? nip : nvp;

  const int t = threadIdx.x;
  const float4* xr4 = (const float4*)(X + (size_t)row * KDIM);
  ushort4* xb4 = (ushort4*)(Xb + (size_t)row * KDIM);

  float4 v = xr4[t];
  float s0 = v.x * v.x + v.y * v.y + v.z * v.z + v.w * v.w;
  float ex = v.x + 1e-6f, ey = v.y + 1e-6f, ez = v.z + 1e-6f, ew = v.w + 1e-6f;
  float s1 = ex * ex + ey * ey + ez * ez + ew * ew;
  ushort4 o;
  o.x = f2bf(v.x); o.y = f2bf(v.y); o.z = f2bf(v.z); o.w = f2bf(v.w);
  xb4[t] = o;

  for (int off = 32; off; off >>= 1) {
    s0 += __shfl_down(s0, off);
    s1 += __shfl_down(s1, off);
  }
  __shared__ float r0[4], r1[4];
  const int w = t >> 6, lane = t & 63;
  if (lane == 0) { r0[w] = s0; r1[w] = s1; }
  __syncthreads();
  if (t == 0) {
    n0[row] = r0[0] + r0[1] + r0[2] + r0[3];
    n1[row] = r1[0] + r1[1] + r1[2] + r1[3];
  }
}

// --- init the atomic max/min buffers ---------------------------------------
__global__ __launch_bounds__(256) void init_kernel(int* __restrict__ same_sq,
                                                   int* __restrict__ diff_sq) {
  const int i = blockIdx.x * 256 + threadIdx.x;  // 8192 total
  same_sq[i] = 0;                                // sq >= 0, so 0 is max-identity
  diff_sq[i] = 0x7F800000;                       // +inf
}

// --- fused 256x256 8-phase GEMM + distance + masked row AND col max/min ----
// A = i_f (rows), B = v_f (+eps norms) (cols).
__global__ __launch_bounds__(512, 2) void tri_gemm(
    const unsigned short* __restrict__ vb, const unsigned short* __restrict__ ib,
    const float* __restrict__ ni, const float* __restrict__ nvp,
    const int* __restrict__ y,
    int* __restrict__ same_sq, int* __restrict__ diff_sq) {
  // K-tile buffer: [256 rows][64 k] bf16, row = 128 B, 8 chunks of 16 B.
  // XOR swizzle: data for (row, chunk) lives at (row, chunk ^ (row&7)).
  // global_load_lds dest stays linear; source address is pre-swizzled.
  __shared__ unsigned short Abuf[2][256][64];   // 64 KiB
  __shared__ unsigned short Bbuf[2][256][64];   // 64 KiB
  __shared__ int   yrow[256], ycol[256];
  __shared__ float nAr[256], nBc[256];

  const unsigned short* Amat = ib;
  const unsigned short* Bmat = vb;

  const int row0 = blockIdx.y * 256;
  const int col0 = blockIdx.x * 256;

  const int t = threadIdx.x;
  const int w = t >> 6, lane = t & 63;
  const int lr = lane & 15, lg = lane >> 4;
  const int wr = w >> 2, wc = w & 3;            // 2 x 4 waves -> 128 x 64 tile

  // stage one half-tile (128 rows x 64 k = 16 KB) = 2 gload16 per thread
  auto stage = [&](const unsigned short* __restrict__ X, int tile0,
                   unsigned short (&buf)[256][64], int h, int k0s) {
#pragma unroll
    for (int r = 0; r < 2; ++r) {
      const int row = h * 128 + r * 64 + (t >> 3);
      const int chunk = t & 7;
      const unsigned short* src =
          X + (size_t)(tile0 + row) * KDIM + k0s + ((chunk ^ (row & 7)) << 3);
      gload16(src, &buf[h * 128 + r * 64 + (w << 3)][0]);
    }
  };
  auto ldA = [&](int c, int mh, int m, int ks) -> bf16x8 {
    const int row = wr * 128 + mh * 64 + m * 16 + lr;
    const int chunk = ((ks << 2) | lg) ^ (row & 7);
    return *(const bf16x8*)&Abuf[c][row][chunk << 3];
  };
  auto ldB = [&](int c, int nh, int n, int ks) -> bf16x8 {
    const int col = wc * 64 + nh * 32 + n * 16 + lr;
    const int chunk = ((ks << 2) | lg) ^ (col & 7);
    return *(const bf16x8*)&Bbuf[c][col][chunk << 3];
  };

  // ---- prologue: tile 0 fully + tile 1 A-h0; labels/norms ----
  stage(Amat, row0, Abuf[0], 0, 0);
  stage(Amat, row0, Abuf[0], 1, 0);
  stage(Bmat, col0, Bbuf[0], 0, 0);
  stage(Bmat, col0, Bbuf[0], 1, 0);
  stage(Amat, row0, Abuf[1], 0, 64);
  if (t < 256) {
    yrow[t] = y[row0 + t];
    nAr[t] = ni[row0 + t];
  } else {
    const int c = t - 256;
    ycol[c] = y[col0 + c];
    nBc[c] = nvp[col0 + c];
  }
  // counted entry: keep Bh1(0)+Ah0(1) in flight; drain LDS writes of y/n.
  asm volatile("s_waitcnt vmcnt(4) lgkmcnt(0)" ::: "memory");
  BAR();

  f32x4 acc[8][4] = {};
  bf16x8 aF[4][2], bF0[2][2], bF1[2][2];

  int cur = 0;
  for (int kt = 0; kt < NT; ++kt) {
    const int nxt = cur ^ 1;
    const int k1 = ((kt + 1) & (NT - 1)) * 64;
    const int k2 = ((kt + 2) & (NT - 1)) * 64;

    // ---- phase 0: quadrant (mh=0) x bF0; stage A-h1(t+1) ----
#pragma unroll
    for (int m = 0; m < 4; ++m) {
      aF[m][0] = ldA(cur, 0, m, 0);
      aF[m][1] = ldA(cur, 0, m, 1);
    }
#pragma unroll
    for (int n = 0; n < 2; ++n) {
      bF0[n][0] = ldB(cur, 0, n, 0);
      bF0[n][1] = ldB(cur, 0, n, 1);
    }
    stage(Amat, row0, Abuf[nxt], 1, k1);
    BAR();
    __builtin_amdgcn_s_setprio(1);
#pragma unroll
    for (int m = 0; m < 4; ++m)
#pragma unroll
      for (int n = 0; n < 2; ++n) {
        acc[m][n] = __builtin_amdgcn_mfma_f32_16x16x32_bf16(aF[m][0], bF0[n][0], acc[m][n], 0, 0, 0);
        acc[m][n] = __builtin_amdgcn_mfma_f32_16x16x32_bf16(aF[m][1], bF0[n][1], acc[m][n], 0, 0, 0);
      }
    __builtin_amdgcn_s_setprio(0);
    // drain B-h1(t) (issued 2 phases ago) for ph1's reads; keep 4 in flight
    asm volatile("s_waitcnt vmcnt(4)" ::: "memory");
    BAR();

    // ---- phase 1: quadrant (mh=0) x bF1; stage B-h0(t+1) ----
#pragma unroll
    for (int n = 0; n < 2; ++n) {
      bF1[n][0] = ldB(cur, 1, n, 0);
      bF1[n][1] = ldB(cur, 1, n, 1);
    }
    stage(Bmat, col0, Bbuf[nxt], 0, k1);
    BAR();
    __builtin_amdgcn_s_setprio(1);
#pragma unroll
    for (int m = 0; m < 4; ++m)
#pragma unroll
      for (int n = 0; n < 2; ++n) {
        acc[m][2 + n] = __builtin_amdgcn_mfma_f32_16x16x32_bf16(aF[m][0], bF1[n][0], acc[m][2 + n], 0, 0, 0);
        acc[m][2 + n] = __builtin_amdgcn_mfma_f32_16x16x32_bf16(aF[m][1], bF1[n][1], acc[m][2 + n], 0, 0, 0);
      }
    __builtin_amdgcn_s_setprio(0);
    BAR();

    // ---- phase 2: quadrant (mh=1) x bF0; stage B-h1(t+1) ----
#pragma unroll
    for (int m = 0; m < 4; ++m) {
      aF[m][0] = ldA(cur, 1, m, 0);
      aF[m][1] = ldA(cur, 1, m, 1);
    }
    stage(Bmat, col0, Bbuf[nxt], 1, k1);
    BAR();
    __builtin_amdgcn_s_setprio(1);
#pragma unroll
    for (int m = 0; m < 4; ++m)
#pragma unroll
      for (int n = 0; n < 2; ++n) {
        acc[4 + m][n] = __builtin_amdgcn_mfma_f32_16x16x32_bf16(aF[m][0], bF0[n][0], acc[4 + m][n], 0, 0, 0);
        acc[4 + m][n] = __builtin_amdgcn_mfma_f32_16x16x32_bf16(aF[m][1], bF0[n][1], acc[4 + m][n], 0, 0, 0);
      }
    __builtin_amdgcn_s_setprio(0);
    BAR();

    // ---- phase 3: quadrant (mh=1) x bF1; stage A-h0(t+2) into buf[cur] ----
    stage(Amat, row0, Abuf[cur], 0, k2);
    BAR();
    __builtin_amdgcn_s_setprio(1);
#pragma unroll
    for (int m = 0; m < 4; ++m)
#pragma unroll
      for (int n = 0; n < 2; ++n) {
        acc[4 + m][2 + n] = __builtin_amdgcn_mfma_f32_16x16x32_bf16(aF[m][0], bF1[n][0], acc[4 + m][2 + n], 0, 0, 0);
        acc[4 + m][2 + n] = __builtin_amdgcn_mfma_f32_16x16x32_bf16(aF[m][1], bF1[n][1], acc[4 + m][2 + n], 0, 0, 0);
      }
    __builtin_amdgcn_s_setprio(0);
    // drain B-h0(t+1) (issued 2 phases ago) for next ph0; keep 4 in flight
    asm volatile("s_waitcnt vmcnt(4)" ::: "memory");
    BAR();

    cur = nxt;
  }
  asm volatile("s_waitcnt vmcnt(0)" ::: "memory");

  // ---- epilogue: sq + mask; row-reduce -> loss_i, col-reduce -> loss_v ----
  const int rbase0 = row0;          // dir0: anchors i_f, indexed by row
  const int rbase1 = MDIM + col0;   // dir1: anchors v_f, indexed by col
  const float INF = __int_as_float(0x7F800000);

  float cs[4], cd[4];               // col partials per N (this lane's 32 rows)
#pragma unroll
  for (int N = 0; N < 4; ++N) { cs[N] = 0.0f; cd[N] = INF; }

#pragma unroll
  for (int M = 0; M < 8; ++M) {
#pragma unroll
    for (int r = 0; r < 4; ++r) {
      const int row_loc = wr * 128 + M * 16 + lg * 4 + r;
      const float na = nAr[row_loc];
      const int yl = yrow[row_loc];
      float smax = 0.0f;
      float dmin = INF;
#pragma unroll
      for (int N = 0; N < 4; ++N) {
        const int col_loc = wc * 64 + N * 16 + lr;
        const float sq = fmaxf(na + nBc[col_loc] - 2.0f * acc[M][N][r], 0.0f);
        if (ycol[col_loc] == yl) {
          smax = fmaxf(smax, sq);
          cs[N] = fmaxf(cs[N], sq);
        } else {
          dmin = fminf(dmin, sq);
          cd[N] = fminf(cd[N], sq);
        }
      }
#pragma unroll
      for (int off = 1; off < 16; off <<= 1) {
        smax = fmaxf(smax, __shfl_xor(smax, off));
        dmin = fminf(dmin, __shfl_xor(dmin, off));
      }
      if (lr == 0) {
        // nonneg floats: int compare == float compare -> order-independent
        atomicMax(&same_sq[rbase0 + row_loc], __float_as_int(smax));
        atomicMin(&diff_sq[rbase0 + row_loc], __float_as_int(dmin));
      }
    }
  }
  // col reduce across lg groups (lanes lane^16, lane^32)
#pragma unroll
  for (int N = 0; N < 4; ++N) {
    float s = cs[N], d = cd[N];
    s = fmaxf(s, __shfl_xor(s, 16)); d = fminf(d, __shfl_xor(d, 16));
    s = fmaxf(s, __shfl_xor(s, 32)); d = fminf(d, __shfl_xor(d, 32));
    if (lane < 16) {
      const int col_loc = wc * 64 + N * 16 + lr;
      atomicMax(&same_sq[rbase1 + col_loc], __float_as_int(s));
      atomicMin(&diff_sq[rbase1 + col_loc], __float_as_int(d));
    }
  }
}

// --- finalize: sqrt, relu, sum ---------------------------------------------
__global__ __launch_bounds__(256) void finalize_kernel(
    const int* __restrict__ same_sq, const int* __restrict__ diff_sq,
    float* __restrict__ out) {
  const int i = blockIdx.x * 256 + threadIdx.x;  // 8192 total
  const float sm = sqrtf(__int_as_float(same_sq[i]));
  const float dm = sqrtf(__int_as_float(diff_sq[i]));  // +inf if no diff label
  float l = fmaxf(sm - dm + 1.2f, 0.0f);
  for (int off = 32; off; off >>= 1) l += __shfl_down(l, off);
  __shared__ float part[4];
  const int w = threadIdx.x >> 6, lane = threadIdx.x & 63;
  if (lane == 0) part[w] = l;
  __syncthreads();
  if (threadIdx.x == 0) atomicAdd(out, part[0] + part[1] + part[2] + part[3]);
}

extern "C" void kernel_launch(void* const* d_in, const int* in_sizes, int n_in,
                              void* d_out, int out_size, void* d_ws, size_t ws_size,
                              hipStream_t stream) {
  const float* vf = (const float*)d_in[0];
  const float* iff = (const float*)d_in[1];
  const int* y = (const int*)d_in[2];
  float* out = (float*)d_out;

  char* ws = (char*)d_ws;
  unsigned short* vb = (unsigned short*)ws;                       // 8 MB
  unsigned short* ib = (unsigned short*)(ws + (8u << 20));        // 8 MB
  float* nv  = (float*)(ws + (16u << 20));
  float* ni  = nv + 4096;
  float* nvp = nv + 2 * 4096;
  float* nip = nv + 3 * 4096;
  int* same_sq = (int*)(nv + 4 * 4096);                           // [2][4096]
  int* diff_sq = same_sq + 2 * 4096;                              // [2][4096]

  hipMemsetAsync(d_out, 0, sizeof(float), stream);
  init_kernel<<<32, 256, 0, stream>>>(same_sq, diff_sq);
  prep_kernel<<<8192, 256, 0, stream>>>(vf, iff, vb, ib, nv, ni, nvp, nip);
  tri_gemm<<<dim3(16, 16), 512, 0, stream>>>(vb, ib, ni, nvp, y,
                                             same_sq, diff_sq);
  finalize_kernel<<<32, 256, 0, stream>>>(same_sq, diff_sq, out);
}

// Round 7
// 55.914 us; speedup vs baseline: 2.5772x; 1.1753x over previous
//
#include <hip/hip_runtime.h>
#include <hip/hip_bf16.h>

// ---------------------------------------------------------------------------
// Triplet loss via ONE 4096^2 sq-distance GEMM (transpose symmetry):
//   G[i,j] = ||i_f[i]||^2 + ||v_f[j]+eps||^2 - 2 i_f[i].(v_f[j]+eps)
//   loss_i: per row i (anchor i_f[i]); loss_v: per col j (anchor v_f[j]).
//   (dir-2 sq differs by 4*eps*(S_i - S_v) ~ 2.6e-4 on sq ~ 2048 -> noise)
// sq-domain trick: reduce on squared distances, sqrt once per anchor.
// R5 schedule, 2-K-tile unrolled (static buffer indices / LDS offsets):
//   ph0: stage A-h1(t+1)->o ; lgkm hint ; end vmcnt(4)
//   ph1: stage B-h0(t+1)->o
//   ph2: stage B-h1(t+1)->o
//   ph3: stage A-h0(t+2)->c ; end vmcnt(4)
// ---------------------------------------------------------------------------

#define MDIM 4096
#define KDIM 1024
#define NT   16      // K-tiles of 64

typedef __attribute__((ext_vector_type(4))) float  f32x4;
typedef __attribute__((ext_vector_type(8))) short  bf16x8;

__device__ __forceinline__ void gload16(const void* g, void* l) {
  __builtin_amdgcn_global_load_lds(
      (const __attribute__((address_space(1))) void*)g,
      (__attribute__((address_space(3))) void*)l,
      16, 0, 0);
}

__device__ __forceinline__ unsigned short f2bf(float x) {
  unsigned int u = __float_as_uint(x);
  unsigned int r = (u + 0x7FFFu + ((u >> 16) & 1u)) >> 16;  // RNE
  return (unsigned short)r;
}

#define BAR() do { asm volatile("" ::: "memory"); \
                   __builtin_amdgcn_s_barrier();  \
                   asm volatile("" ::: "memory"); } while (0)

// --- prep: wave-per-row f32 -> bf16 + row norms; fused init of reduce bufs --
__global__ __launch_bounds__(256) void prep_kernel(
    const float* __restrict__ vf, const float* __restrict__ iff,
    unsigned short* __restrict__ vb, unsigned short* __restrict__ ib,
    float* __restrict__ ni, float* __restrict__ nvp,
    int* __restrict__ same_sq, int* __restrict__ diff_sq,
    float* __restrict__ out) {
  const int wid = blockIdx.x * 4 + (threadIdx.x >> 6);  // 0..8191, wave = row
  const int lane = threadIdx.x & 63;
  const int mat = wid >> 12;              // 0 = v_f, 1 = i_f
  const int row = wid & 4095;
  const float* X = mat ? iff : vf;
  unsigned short* Xb = mat ? ib : vb;

  const float4* xr4 = (const float4*)(X + (size_t)row * KDIM);
  ushort4* xb4 = (ushort4*)(Xb + (size_t)row * KDIM);

  float4 v = xr4[lane];
  ushort4 o;
  o.x = f2bf(v.x); o.y = f2bf(v.y); o.z = f2bf(v.z); o.w = f2bf(v.w);
  xb4[lane] = o;

  float s;
  if (mat) {  // i_f: plain norm
    s = v.x * v.x + v.y * v.y + v.z * v.z + v.w * v.w;
  } else {    // v_f: norm of (x + eps)
    float ex = v.x + 1e-6f, ey = v.y + 1e-6f, ez = v.z + 1e-6f, ew = v.w + 1e-6f;
    s = ex * ex + ey * ey + ez * ez + ew * ew;
  }
  for (int off = 32; off; off >>= 1) s += __shfl_down(s, off);
  if (lane == 0) {
    if (mat) ni[row] = s; else nvp[row] = s;
  }

  // fused init (first 32 blocks cover the 8192-entry reduce buffers)
  const int gi = blockIdx.x * 256 + threadIdx.x;
  if (gi < 2 * MDIM) {
    same_sq[gi] = 0;             // sq >= 0: 0 is max-identity
    diff_sq[gi] = 0x7F800000;    // +inf
  }
  if (gi == 0) out[0] = 0.0f;
}

// --- fused 256x256 8-phase GEMM + distance + masked row AND col max/min ----
// A = i_f (rows), B = v_f (+eps norms) (cols).
__global__ __launch_bounds__(512, 2) void tri_gemm(
    const unsigned short* __restrict__ vb, const unsigned short* __restrict__ ib,
    const float* __restrict__ ni, const float* __restrict__ nvp,
    const int* __restrict__ y,
    int* __restrict__ same_sq, int* __restrict__ diff_sq) {
  // K-tile buffer: [256 rows][64 k] bf16, row = 128 B, 8 chunks of 16 B.
  // XOR swizzle: data for (row, chunk) lives at (row, chunk ^ (row&7)).
  // global_load_lds dest stays linear; source address is pre-swizzled.
  __shared__ unsigned short Abuf[2][256][64];   // 64 KiB
  __shared__ unsigned short Bbuf[2][256][64];   // 64 KiB
  __shared__ int   yrow[256], ycol[256];
  __shared__ float nAr[256], nBc[256];

  const unsigned short* Amat = ib;
  const unsigned short* Bmat = vb;

  const int row0 = blockIdx.y * 256;
  const int col0 = blockIdx.x * 256;

  const int t = threadIdx.x;
  const int w = t >> 6, lane = t & 63;
  const int lr = lane & 15, lg = lane >> 4;
  const int wr = w >> 2, wc = w & 3;            // 2 x 4 waves -> 128 x 64 tile

  // stage one half-tile (128 rows x 64 k = 16 KB) = 2 gload16 per thread
  auto stage = [&](const unsigned short* __restrict__ X, int tile0,
                   unsigned short (&buf)[256][64], int h, int k0s) {
#pragma unroll
    for (int r = 0; r < 2; ++r) {
      const int row = h * 128 + r * 64 + (t >> 3);
      const int chunk = t & 7;
      const unsigned short* src =
          X + (size_t)(tile0 + row) * KDIM + k0s + ((chunk ^ (row & 7)) << 3);
      gload16(src, &buf[h * 128 + r * 64 + (w << 3)][0]);
    }
  };
  auto ldA = [&](int c, int mh, int m, int ks) -> bf16x8 {
    const int row = wr * 128 + mh * 64 + m * 16 + lr;
    const int chunk = ((ks << 2) | lg) ^ (row & 7);
    return *(const bf16x8*)&Abuf[c][row][chunk << 3];
  };
  auto ldB = [&](int c, int nh, int n, int ks) -> bf16x8 {
    const int col = wc * 64 + nh * 32 + n * 16 + lr;
    const int chunk = ((ks << 2) | lg) ^ (col & 7);
    return *(const bf16x8*)&Bbuf[c][col][chunk << 3];
  };

  // ---- prologue: tile 0 fully + tile 1 A-h0; labels/norms ----
  stage(Amat, row0, Abuf[0], 0, 0);
  stage(Amat, row0, Abuf[0], 1, 0);
  stage(Bmat, col0, Bbuf[0], 0, 0);
  stage(Bmat, col0, Bbuf[0], 1, 0);
  stage(Amat, row0, Abuf[1], 0, 64);
  if (t < 256) {
    yrow[t] = y[row0 + t];
    nAr[t] = ni[row0 + t];
  } else {
    const int c = t - 256;
    ycol[c] = y[col0 + c];
    nBc[c] = nvp[col0 + c];
  }
  // counted entry: keep Bh1(0)+Ah0(1) in flight; drain LDS writes of y/n.
  asm volatile("s_waitcnt vmcnt(4) lgkmcnt(0)" ::: "memory");
  BAR();

  f32x4 acc[8][4] = {};
  bf16x8 aF[4][2], bF0[2][2], bF1[2][2];

// One K-tile = 4 phases. C: buffer of tile t (literal 0/1); K1/K2: k-offsets
// of tiles t+1 / t+2 (runtime ok -- global source addressing only).
#define DO_TILE(C, K1, K2)                                                     \
  do {                                                                         \
    /* ph0: quadrant (mh=0) x bF0; stage A-h1(t+1) */                          \
    _Pragma("unroll") for (int m = 0; m < 4; ++m) {                            \
      aF[m][0] = ldA(C, 0, m, 0);                                              \
      aF[m][1] = ldA(C, 0, m, 1);                                              \
    }                                                                          \
    _Pragma("unroll") for (int n = 0; n < 2; ++n) {                            \
      bF0[n][0] = ldB(C, 0, n, 0);                                             \
      bF0[n][1] = ldB(C, 0, n, 1);                                             \
    }                                                                          \
    stage(Amat, row0, Abuf[1 - (C)], 1, (K1));                                 \
    asm volatile("s_waitcnt lgkmcnt(8)" ::: "memory");                         \
    BAR();                                                                     \
    __builtin_amdgcn_s_setprio(1);                                             \
    _Pragma("unroll") for (int m = 0; m < 4; ++m)                              \
      _Pragma("unroll") for (int n = 0; n < 2; ++n) {                          \
        acc[m][n] = __builtin_amdgcn_mfma_f32_16x16x32_bf16(                   \
            aF[m][0], bF0[n][0], acc[m][n], 0, 0, 0);                          \
        acc[m][n] = __builtin_amdgcn_mfma_f32_16x16x32_bf16(                   \
            aF[m][1], bF0[n][1], acc[m][n], 0, 0, 0);                          \
      }                                                                        \
    __builtin_amdgcn_s_setprio(0);                                             \
    asm volatile("s_waitcnt vmcnt(4)" ::: "memory");                           \
    BAR();                                                                     \
    /* ph1: quadrant (mh=0) x bF1; stage B-h0(t+1) */                          \
    _Pragma("unroll") for (int n = 0; n < 2; ++n) {                            \
      bF1[n][0] = ldB(C, 1, n, 0);                                             \
      bF1[n][1] = ldB(C, 1, n, 1);                                             \
    }                                                                          \
    stage(Bmat, col0, Bbuf[1 - (C)], 0, (K1));                                 \
    BAR();                                                                     \
    __builtin_amdgcn_s_setprio(1);                                             \
    _Pragma("unroll") for (int m = 0; m < 4; ++m)                              \
      _Pragma("unroll") for (int n = 0; n < 2; ++n) {                          \
        acc[m][2 + n] = __builtin_amdgcn_mfma_f32_16x16x32_bf16(               \
            aF[m][0], bF1[n][0], acc[m][2 + n], 0, 0, 0);                      \
        acc[m][2 + n] = __builtin_amdgcn_mfma_f32_16x16x32_bf16(               \
            aF[m][1], bF1[n][1], acc[m][2 + n], 0, 0, 0);                      \
      }                                                                        \
    __builtin_amdgcn_s_setprio(0);                                             \
    BAR();                                                                     \
    /* ph2: quadrant (mh=1) x bF0; stage B-h1(t+1) */                          \
    _Pragma("unroll") for (int m = 0; m < 4; ++m) {                            \
      aF[m][0] = ldA(C, 1, m, 0);                                              \
      aF[m][1] = ldA(C, 1, m, 1);                                              \
    }                                                                          \
    stage(Bmat, col0, Bbuf[1 - (C)], 1, (K1));                                 \
    BAR();                                                                     \
    __builtin_amdgcn_s_setprio(1);                                             \
    _Pragma("unroll") for (int m = 0; m < 4; ++m)                              \
      _Pragma("unroll") for (int n = 0; n < 2; ++n) {                          \
        acc[4 + m][n] = __builtin_amdgcn_mfma_f32_16x16x32_bf16(               \
            aF[m][0], bF0[n][0], acc[4 + m][n], 0, 0, 0);                      \
        acc[4 + m][n] = __builtin_amdgcn_mfma_f32_16x16x32_bf16(               \
            aF[m][1], bF0[n][1], acc[4 + m][n], 0, 0, 0);                      \
      }                                                                        \
    __builtin_amdgcn_s_setprio(0);                                             \
    BAR();                                                                     \
    /* ph3: quadrant (mh=1) x bF1; stage A-h0(t+2) into buf C */               \
    stage(Amat, row0, Abuf[C], 0, (K2));                                       \
    BAR();                                                                     \
    __builtin_amdgcn_s_setprio(1);                                             \
    _Pragma("unroll") for (int m = 0; m < 4; ++m)                              \
      _Pragma("unroll") for (int n = 0; n < 2; ++n) {                          \
        acc[4 + m][2 + n] = __builtin_amdgcn_mfma_f32_16x16x32_bf16(           \
            aF[m][0], bF1[n][0], acc[4 + m][2 + n], 0, 0, 0);                  \
        acc[4 + m][2 + n] = __builtin_amdgcn_mfma_f32_16x16x32_bf16(           \
            aF[m][1], bF1[n][1], acc[4 + m][2 + n], 0, 0, 0);                  \
      }                                                                        \
    __builtin_amdgcn_s_setprio(0);                                             \
    asm volatile("s_waitcnt vmcnt(4)" ::: "memory");                           \
    BAR();                                                                     \
  } while (0)

  for (int kt = 0; kt < NT; kt += 2) {
    const int ka = ((kt + 1) & (NT - 1)) * 64;
    const int kb = ((kt + 2) & (NT - 1)) * 64;
    const int kc = ((kt + 3) & (NT - 1)) * 64;
    DO_TILE(0, ka, kb);   // even tile lives in buf 0
    DO_TILE(1, kb, kc);   // odd tile lives in buf 1
  }
#undef DO_TILE
  asm volatile("s_waitcnt vmcnt(0)" ::: "memory");

  // ---- epilogue: sq + mask; row-reduce -> loss_i, col-reduce -> loss_v ----
  const int rbase0 = row0;          // dir0: anchors i_f, indexed by row
  const int rbase1 = MDIM + col0;   // dir1: anchors v_f, indexed by col
  const float INF = __int_as_float(0x7F800000);

  float cs[4], cd[4];               // col partials per N (this lane's 32 rows)
#pragma unroll
  for (int N = 0; N < 4; ++N) { cs[N] = 0.0f; cd[N] = INF; }

#pragma unroll
  for (int M = 0; M < 8; ++M) {
#pragma unroll
    for (int r = 0; r < 4; ++r) {
      const int row_loc = wr * 128 + M * 16 + lg * 4 + r;
      const float na = nAr[row_loc];
      const int yl = yrow[row_loc];
      float smax = 0.0f;
      float dmin = INF;
#pragma unroll
      for (int N = 0; N < 4; ++N) {
        const int col_loc = wc * 64 + N * 16 + lr;
        const float sq = fmaxf(na + nBc[col_loc] - 2.0f * acc[M][N][r], 0.0f);
        if (ycol[col_loc] == yl) {
          smax = fmaxf(smax, sq);
          cs[N] = fmaxf(cs[N], sq);
        } else {
          dmin = fminf(dmin, sq);
          cd[N] = fminf(cd[N], sq);
        }
      }
#pragma unroll
      for (int off = 1; off < 16; off <<= 1) {
        smax = fmaxf(smax, __shfl_xor(smax, off));
        dmin = fminf(dmin, __shfl_xor(dmin, off));
      }
      if (lr == 0) {
        // nonneg floats: int compare == float compare -> order-independent
        atomicMax(&same_sq[rbase0 + row_loc], __float_as_int(smax));
        atomicMin(&diff_sq[rbase0 + row_loc], __float_as_int(dmin));
      }
    }
  }
  // col reduce across lg groups (lanes lane^16, lane^32)
#pragma unroll
  for (int N = 0; N < 4; ++N) {
    float s = cs[N], d = cd[N];
    s = fmaxf(s, __shfl_xor(s, 16)); d = fminf(d, __shfl_xor(d, 16));
    s = fmaxf(s, __shfl_xor(s, 32)); d = fminf(d, __shfl_xor(d, 32));
    if (lane < 16) {
      const int col_loc = wc * 64 + N * 16 + lr;
      atomicMax(&same_sq[rbase1 + col_loc], __float_as_int(s));
      atomicMin(&diff_sq[rbase1 + col_loc], __float_as_int(d));
    }
  }
}

// --- finalize: sqrt, relu, sum ---------------------------------------------
__global__ __launch_bounds__(256) void finalize_kernel(
    const int* __restrict__ same_sq, const int* __restrict__ diff_sq,
    float* __restrict__ out) {
  const int i = blockIdx.x * 256 + threadIdx.x;  // 8192 total
  const float sm = sqrtf(__int_as_float(same_sq[i]));
  const float dm = sqrtf(__int_as_float(diff_sq[i]));  // +inf if no diff label
  float l = fmaxf(sm - dm + 1.2f, 0.0f);
  for (int off = 32; off; off >>= 1) l += __shfl_down(l, off);
  __shared__ float part[4];
  const int w = threadIdx.x >> 6, lane = threadIdx.x & 63;
  if (lane == 0) part[w] = l;
  __syncthreads();
  if (threadIdx.x == 0) atomicAdd(out, part[0] + part[1] + part[2] + part[3]);
}

extern "C" void kernel_launch(void* const* d_in, const int* in_sizes, int n_in,
                              void* d_out, int out_size, void* d_ws, size_t ws_size,
                              hipStream_t stream) {
  const float* vf = (const float*)d_in[0];
  const float* iff = (const float*)d_in[1];
  const int* y = (const int*)d_in[2];
  float* out = (float*)d_out;

  char* ws = (char*)d_ws;
  unsigned short* vb = (unsigned short*)ws;                       // 8 MB
  unsigned short* ib = (unsigned short*)(ws + (8u << 20));        // 8 MB
  float* nv  = (float*)(ws + (16u << 20));
  float* ni  = nv + 4096;
  float* nvp = nv + 2 * 4096;
  int* same_sq = (int*)(nv + 4 * 4096);                           // [2][4096]
  int* diff_sq = same_sq + 2 * 4096;                              // [2][4096]

  prep_kernel<<<2048, 256, 0, stream>>>(vf, iff, vb, ib, ni, nvp,
                                        same_sq, diff_sq, out);
  tri_gemm<<<dim3(16, 16), 512, 0, stream>>>(vb, ib, ni, nvp, y,
                                             same_sq, diff_sq);
  finalize_kernel<<<32, 256, 0, stream>>>(same_sq, diff_sq, out);
}